// Round 10
// baseline (84.131 us; speedup 1.0000x reference)
//
#include <hip/hip_runtime.h>
#include <hip/hip_bf16.h>

typedef __attribute__((ext_vector_type(8))) short short8;
typedef __attribute__((ext_vector_type(4))) float f32x4;
typedef __attribute__((ext_vector_type(4))) unsigned int u32x4;

#define HWPIX 147456   // 384*384
#define NC 64
#define NO 64
#define NM 4
#define EPSV 1e-5f

// f32 pair -> packed bf16x2, round-to-nearest-even (hardware instruction).
static __device__ __forceinline__ unsigned int cvt_pk(float a, float b) {
    unsigned int r;
    asm("v_cvt_pk_bf16_f32 %0, %1, %2" : "=v"(r) : "v"(a), "v"(b));
    return r;
}
static __device__ __forceinline__ float asf(unsigned int u) {
    return __uint_as_float(u);
}

// raw barrier: LDS-visibility only, keeps global loads in flight (T4)
#define BAR() do { asm volatile("s_waitcnt lgkmcnt(0)" ::: "memory"); \
                   __builtin_amdgcn_s_barrier();                      \
                   asm volatile("" ::: "memory"); } while (0)

// R9-proven skeleton: LayerNorm -> stacked 1x1 conv -> sum_m relu(z-q).
// A = xn-hi (LDS dbuf, XOR-swizzled), B = gamma*W split hi/lo (regs),
// beta folded into acc init.  2-term split: xh*Wh + xh*Wl.
// Epilogue: sum_m max(z,q) - 4q.  1-deep prefetch, 1 raw barrier/iter.
// R10: 16 hoisted base pointers + full unroll -> all load/store offsets are
// compile-time immediates (zero per-iter address VALU); prefetch before BAR.
__global__ __launch_bounds__(256) void dnm_fused(
    const float* __restrict__ x, const float* __restrict__ Wg,
    const float* __restrict__ qp, const float* __restrict__ gamma,
    const float* __restrict__ beta, float* __restrict__ out)
{
    // per buffer: xn-hi. Row = pixel (64 rows x 128B of bf16[64]),
    // 16B slots swizzled: byte = r*128 + ((slot ^ (r&7))<<4)
    __shared__ __align__(16) unsigned char lds[2][8192];

    const int tid = threadIdx.x;
    const int wv  = tid >> 6;        // wave 0..3 (owns o-slice wv*16..+16)
    const int ln  = tid & 63;
    const int p16 = ln & 15;
    const int g4  = ln >> 4;         // k-chunk group 0..3

    const int bid = blockIdx.x;      // 1152 blocks: 288 strips of 512 px per image
    const int b       = bid / 288;
    const int pixbase = (bid % 288) * 512;

    const float qv = qp[0];
    const float q4 = 4.0f * qv;

    // ---- B operand: W' = gamma .* W split hi/lo; bias[m] = sum_c beta_c*W[m][o][c]
    // lane holds row o = wv*16+p16, k = ch*32 + g4*8 + j
    f32x4 gA[2], gB[2], bA[2], bB[2];
#pragma unroll
    for (int ch = 0; ch < 2; ++ch) {
        gA[ch] = *(const f32x4*)(gamma + ch * 32 + g4 * 8);
        gB[ch] = *(const f32x4*)(gamma + ch * 32 + g4 * 8 + 4);
        bA[ch] = *(const f32x4*)(beta  + ch * 32 + g4 * 8);
        bB[ch] = *(const f32x4*)(beta  + ch * 32 + g4 * 8 + 4);
    }
    short8 wh[NM][2], wl[NM][2];
    float bias[NM];
#pragma unroll
    for (int m = 0; m < NM; ++m) {
        float bsum = 0.f;
#pragma unroll
        for (int ch = 0; ch < 2; ++ch) {
            const float* wp = Wg + ((m * NO + (wv * 16 + p16)) * NC + ch * 32 + g4 * 8);
            f32x4 a = *(const f32x4*)(wp);
            f32x4 c = *(const f32x4*)(wp + 4);
            float f[8]  = {a[0], a[1], a[2], a[3], c[0], c[1], c[2], c[3]};
            float gg[8] = {gA[ch][0], gA[ch][1], gA[ch][2], gA[ch][3],
                           gB[ch][0], gB[ch][1], gB[ch][2], gB[ch][3]};
            float bb[8] = {bA[ch][0], bA[ch][1], bA[ch][2], bA[ch][3],
                           bB[ch][0], bB[ch][1], bB[ch][2], bB[ch][3]};
            float wq[8];
#pragma unroll
            for (int j = 0; j < 8; ++j) {
                bsum += bb[j] * f[j];
                wq[j] = gg[j] * f[j];
            }
            u32x4 hu, lu;
#pragma unroll
            for (int p = 0; p < 4; ++p) {
                unsigned int h = cvt_pk(wq[2*p], wq[2*p+1]);
                float r0 = wq[2*p]   - asf(h << 16);          // bf2f(hi.lo) free
                float r1 = wq[2*p+1] - asf(h & 0xffff0000u);  // bf2f(hi.hi) free
                hu[p] = h;
                lu[p] = cvt_pk(r0, r1);
            }
            wh[m][ch] = __builtin_bit_cast(short8, hu);
            wl[m][ch] = __builtin_bit_cast(short8, lu);
        }
        bsum += __shfl_xor(bsum, 16);
        bsum += __shfl_xor(bsum, 32);   // full sum over c for this o
        bias[m] = bsum;
    }

    const float* xpl = x + (size_t)b * NC * HWPIX + pixbase + wv * 16 + p16
                         + (size_t)(g4 * 16) * HWPIX;
    float* const outw = out + (size_t)b * NO * HWPIX
                            + (size_t)(wv * 16 + p16) * HWPIX + pixbase;

    // 16 hoisted per-lane base pointers; all per-iter offsets are immediates
    const float* px[16];
#pragma unroll
    for (int i = 0; i < 16; ++i) px[i] = xpl + (size_t)i * HWPIX;

    const int r  = wv * 16 + p16;    // LDS row this lane writes
    const int rk = r & 7;

    // prologue: loads for it=0
    float xv[16];
#pragma unroll
    for (int i = 0; i < 16; ++i) xv[i] = px[i][0];

#pragma unroll
    for (int it = 0; it < 8; ++it) {
        unsigned char* buf = lds[it & 1];

        // ---- LN on prefetched xv (this wave's 16-px subtile, once per pixel)
        {
            float s1 = 0.f, s2 = 0.f;
#pragma unroll
            for (int i = 0; i < 16; ++i) { s1 += xv[i]; s2 += xv[i] * xv[i]; }
            s1 += __shfl_xor(s1, 16);  s2 += __shfl_xor(s2, 16);
            s1 += __shfl_xor(s1, 32);  s2 += __shfl_xor(s2, 32);
            const float mu  = s1 * (1.f / 64.f);
            const float var = s2 * (1.f / 64.f) - mu * mu;   // biased (torch)
            const float rs  = rsqrtf(var + EPSV);
            u32x4 h0, h1;
#pragma unroll
            for (int p = 0; p < 4; ++p) {
                h0[p] = cvt_pk((xv[2*p]     - mu) * rs, (xv[2*p+1] - mu) * rs);
                h1[p] = cvt_pk((xv[8+2*p]   - mu) * rs, (xv[9+2*p] - mu) * rs);
            }
            const int s0 = g4 * 2;
            *(u32x4*)(buf + r * 128 + (((s0    ) ^ rk) << 4)) = h0;
            *(u32x4*)(buf + r * 128 + (((s0 + 1) ^ rk) << 4)) = h1;
        }

        // ---- prefetch next tile's x BEFORE the barrier (stays in flight;
        // BAR waits lgkmcnt only). xv fully consumed by the cvt_pk above.
        if (it < 7) {
#pragma unroll
            for (int i = 0; i < 16; ++i) xv[i] = px[i][(it + 1) * 64];
        }
        BAR();

        // ---- MFMA: wave covers its o-slice for all 4 pixel-subtiles
#pragma unroll
        for (int ps = 0; ps < 4; ++ps) {
            const int row = ps * 16 + p16;
            const int rwk = row & 7;
            short8 ah[2];
#pragma unroll
            for (int ch = 0; ch < 2; ++ch) {
                const int slot = ch * 4 + g4;
                ah[ch] = *(const short8*)(buf + row * 128 + ((slot ^ rwk) << 4));
            }
            f32x4 acc[NM];
#pragma unroll
            for (int m = 0; m < NM; ++m) {
                f32x4 a = {bias[m], bias[m], bias[m], bias[m]};
#pragma unroll
                for (int ch = 0; ch < 2; ++ch) {
                    // 2-term split: xh*Wh + xh*Wl (R5/R8/R9-proven numerics)
                    a = __builtin_amdgcn_mfma_f32_16x16x32_bf16(ah[ch], wh[m][ch], a, 0, 0, 0);
                    a = __builtin_amdgcn_mfma_f32_16x16x32_bf16(ah[ch], wl[m][ch], a, 0, 0, 0);
                }
                acc[m] = a;
            }
            // sum_m relu(z-q) = sum_m max(z,q) - 4q (R4-proven);
            // D: col(p16)=o-local, row(g4*4+rr)=pixel-local
            f32x4 v;
#pragma unroll
            for (int rr = 0; rr < 4; ++rr) {
                v[rr] = (fmaxf(acc[0][rr], qv) + fmaxf(acc[1][rr], qv))
                      + (fmaxf(acc[2][rr], qv) + fmaxf(acc[3][rr], qv)) - q4;
            }
            *(f32x4*)(outw + it * 64 + ps * 16 + g4 * 4) = v;   // 4 consecutive px
        }
        // single barrier per iter: buffer b reused at it+2 is ordered by
        // BAR(it+1), which every wave reaches only after its it-phase reads.
    }
}

extern "C" void kernel_launch(void* const* d_in, const int* in_sizes, int n_in,
                              void* d_out, int out_size, void* d_ws, size_t ws_size,
                              hipStream_t stream) {
    const float* x     = (const float*)d_in[0];
    const float* Wg    = (const float*)d_in[1];
    const float* q     = (const float*)d_in[2];
    const float* gamma = (const float*)d_in[3];
    const float* beta  = (const float*)d_in[4];
    float* out = (float*)d_out;

    // 4 images * 288 strips of 512 px = 1152 blocks
    dnm_fused<<<dim3(1152), dim3(256), 0, stream>>>(x, Wg, q, gamma, beta, out);
}

// Round 11
// 79.840 us; speedup vs baseline: 1.0538x; 1.0538x over previous
//
#include <hip/hip_runtime.h>
#include <hip/hip_bf16.h>

typedef __attribute__((ext_vector_type(8))) short short8;
typedef __attribute__((ext_vector_type(4))) float f32x4;
typedef __attribute__((ext_vector_type(4))) unsigned int u32x4;

#define HWPIX 147456   // 384*384
#define NC 64
#define NO 64
#define NM 4
#define EPSV 1e-5f

// f32 pair -> packed bf16x2, round-to-nearest-even (hardware instruction).
static __device__ __forceinline__ unsigned int cvt_pk(float a, float b) {
    unsigned int r;
    asm("v_cvt_pk_bf16_f32 %0, %1, %2" : "=v"(r) : "v"(a), "v"(b));
    return r;
}
static __device__ __forceinline__ float asf(unsigned int u) {
    return __uint_as_float(u);
}

// raw barrier: LDS-visibility only, keeps global loads in flight (T4)
#define BAR() do { asm volatile("s_waitcnt lgkmcnt(0)" ::: "memory"); \
                   __builtin_amdgcn_s_barrier();                      \
                   asm volatile("" ::: "memory"); } while (0)

// R9-proven skeleton: LayerNorm -> stacked 1x1 conv -> sum_m relu(z-q).
// A = xn-hi (LDS dbuf, XOR-swizzled), B = gamma*W split hi/lo (regs),
// beta folded into acc init.  2-term split: xh*Wh + xh*Wl.
// Epilogue: sum_m max(z,q) - 4q.  1-deep prefetch after BAR.
// R11: 128-px phases (2x16 px LN per wave, 8 MFMA subtiles) -> MFMA issue
// (~1000cy) covers HBM latency (~900cy); barriers halve to 4/block.
__global__ __launch_bounds__(256) void dnm_fused(
    const float* __restrict__ x, const float* __restrict__ Wg,
    const float* __restrict__ qp, const float* __restrict__ gamma,
    const float* __restrict__ beta, float* __restrict__ out)
{
    // per buffer: xn-hi, 128 rows (pixel) x 128B (bf16[64] channels),
    // 16B slots swizzled: byte = row*128 + ((slot ^ (row&7))<<4)
    __shared__ __align__(16) unsigned char lds[2][16384];

    const int tid = threadIdx.x;
    const int wv  = tid >> 6;        // wave 0..3 (owns o-slice wv*16..+16)
    const int ln  = tid & 63;
    const int p16 = ln & 15;
    const int g4  = ln >> 4;         // k-chunk group 0..3

    const int bid = blockIdx.x;      // 1152 blocks: 288 strips of 512 px per image
    const int b       = bid / 288;
    const int pixbase = (bid % 288) * 512;

    const float qv = qp[0];
    const float q4 = 4.0f * qv;

    // ---- B operand: W' = gamma .* W split hi/lo; bias[m] = sum_c beta_c*W[m][o][c]
    // lane holds row o = wv*16+p16, k = ch*32 + g4*8 + j
    f32x4 gA[2], gB[2], bA[2], bB[2];
#pragma unroll
    for (int ch = 0; ch < 2; ++ch) {
        gA[ch] = *(const f32x4*)(gamma + ch * 32 + g4 * 8);
        gB[ch] = *(const f32x4*)(gamma + ch * 32 + g4 * 8 + 4);
        bA[ch] = *(const f32x4*)(beta  + ch * 32 + g4 * 8);
        bB[ch] = *(const f32x4*)(beta  + ch * 32 + g4 * 8 + 4);
    }
    short8 wh[NM][2], wl[NM][2];
    float bias[NM];
#pragma unroll
    for (int m = 0; m < NM; ++m) {
        float bsum = 0.f;
#pragma unroll
        for (int ch = 0; ch < 2; ++ch) {
            const float* wp = Wg + ((m * NO + (wv * 16 + p16)) * NC + ch * 32 + g4 * 8);
            f32x4 a = *(const f32x4*)(wp);
            f32x4 c = *(const f32x4*)(wp + 4);
            float f[8]  = {a[0], a[1], a[2], a[3], c[0], c[1], c[2], c[3]};
            float gg[8] = {gA[ch][0], gA[ch][1], gA[ch][2], gA[ch][3],
                           gB[ch][0], gB[ch][1], gB[ch][2], gB[ch][3]};
            float bb[8] = {bA[ch][0], bA[ch][1], bA[ch][2], bA[ch][3],
                           bB[ch][0], bB[ch][1], bB[ch][2], bB[ch][3]};
            float wq[8];
#pragma unroll
            for (int j = 0; j < 8; ++j) {
                bsum += bb[j] * f[j];
                wq[j] = gg[j] * f[j];
            }
            u32x4 hu, lu;
#pragma unroll
            for (int p = 0; p < 4; ++p) {
                unsigned int h = cvt_pk(wq[2*p], wq[2*p+1]);
                float r0 = wq[2*p]   - asf(h << 16);          // bf2f(hi.lo) free
                float r1 = wq[2*p+1] - asf(h & 0xffff0000u);  // bf2f(hi.hi) free
                hu[p] = h;
                lu[p] = cvt_pk(r0, r1);
            }
            wh[m][ch] = __builtin_bit_cast(short8, hu);
            wl[m][ch] = __builtin_bit_cast(short8, lu);
        }
        bsum += __shfl_xor(bsum, 16);
        bsum += __shfl_xor(bsum, 32);   // full sum over c for this o
        bias[m] = bsum;
    }

    const float* xpl = x + (size_t)b * NC * HWPIX + pixbase + wv * 16 + p16
                         + (size_t)(g4 * 16) * HWPIX;
    float* const outw = out + (size_t)b * NO * HWPIX
                            + (size_t)(wv * 16 + p16) * HWPIX + pixbase;

    const int r  = wv * 16 + p16;    // LDS base row this lane writes (set 0)
    const int rk  = r & 7;
    const int r1  = 64 + r;          // set-1 row
    const int rk1 = r1 & 7;          // == rk (64 ≡ 0 mod 8), kept explicit

    // prologue: loads for it=0 (two 16-px sets, 64 px apart per wave)
    float xv[2][16];
#pragma unroll
    for (int i = 0; i < 16; ++i) {
        xv[0][i] = xpl[(size_t)i * HWPIX];
        xv[1][i] = xpl[(size_t)i * HWPIX + 64];
    }

#pragma unroll 1
    for (int it = 0; it < 4; ++it) {
        unsigned char* buf = lds[it & 1];

        // ---- LN on prefetched xv: two 16-px sets per wave
#pragma unroll
        for (int s = 0; s < 2; ++s) {
            float s1 = 0.f, s2 = 0.f;
#pragma unroll
            for (int i = 0; i < 16; ++i) { s1 += xv[s][i]; s2 += xv[s][i] * xv[s][i]; }
            s1 += __shfl_xor(s1, 16);  s2 += __shfl_xor(s2, 16);
            s1 += __shfl_xor(s1, 32);  s2 += __shfl_xor(s2, 32);
            const float mu  = s1 * (1.f / 64.f);
            const float var = s2 * (1.f / 64.f) - mu * mu;   // biased (torch)
            const float rs  = rsqrtf(var + EPSV);
            u32x4 h0, h1;
#pragma unroll
            for (int p = 0; p < 4; ++p) {
                h0[p] = cvt_pk((xv[s][2*p]   - mu) * rs, (xv[s][2*p+1] - mu) * rs);
                h1[p] = cvt_pk((xv[s][8+2*p] - mu) * rs, (xv[s][9+2*p] - mu) * rs);
            }
            const int row = s ? r1 : r;
            const int rw  = s ? rk1 : rk;
            const int s0 = g4 * 2;
            *(u32x4*)(buf + row * 128 + (((s0    ) ^ rw) << 4)) = h0;
            *(u32x4*)(buf + row * 128 + (((s0 + 1) ^ rw) << 4)) = h1;
        }
        BAR();

        // ---- prefetch next phase's x (32 loads, in flight across 8 MFMA subtiles)
        if (it < 3) {
            const float* xp = xpl + (it + 1) * 128;
#pragma unroll
            for (int i = 0; i < 16; ++i) {
                xv[0][i] = xp[(size_t)i * HWPIX];
                xv[1][i] = xp[(size_t)i * HWPIX + 64];
            }
        }

        // ---- MFMA: wave covers its o-slice for all 8 pixel-subtiles
#pragma unroll 1
        for (int ps = 0; ps < 8; ++ps) {
            const int row = ps * 16 + p16;
            const int rwk = row & 7;
            short8 ah[2];
#pragma unroll
            for (int ch = 0; ch < 2; ++ch) {
                const int slot = ch * 4 + g4;
                ah[ch] = *(const short8*)(buf + row * 128 + ((slot ^ rwk) << 4));
            }
            f32x4 acc[NM];
#pragma unroll
            for (int m = 0; m < NM; ++m) {
                f32x4 a = {bias[m], bias[m], bias[m], bias[m]};
#pragma unroll
                for (int ch = 0; ch < 2; ++ch) {
                    // 2-term split: xh*Wh + xh*Wl (R5/R8/R9-proven numerics)
                    a = __builtin_amdgcn_mfma_f32_16x16x32_bf16(ah[ch], wh[m][ch], a, 0, 0, 0);
                    a = __builtin_amdgcn_mfma_f32_16x16x32_bf16(ah[ch], wl[m][ch], a, 0, 0, 0);
                }
                acc[m] = a;
            }
            // sum_m relu(z-q) = sum_m max(z,q) - 4q (R4-proven);
            // D: col(p16)=o-local, row(g4*4+rr)=pixel-local
            f32x4 v;
#pragma unroll
            for (int rr = 0; rr < 4; ++rr) {
                v[rr] = (fmaxf(acc[0][rr], qv) + fmaxf(acc[1][rr], qv))
                      + (fmaxf(acc[2][rr], qv) + fmaxf(acc[3][rr], qv)) - q4;
            }
            *(f32x4*)(outw + it * 128 + ps * 16 + g4 * 4) = v;   // 4 consecutive px
        }
        // single barrier per iter: buffer b reused at it+2 is ordered by
        // BAR(it+1), which every wave reaches only after its it-phase reads.
    }
}

extern "C" void kernel_launch(void* const* d_in, const int* in_sizes, int n_in,
                              void* d_out, int out_size, void* d_ws, size_t ws_size,
                              hipStream_t stream) {
    const float* x     = (const float*)d_in[0];
    const float* Wg    = (const float*)d_in[1];
    const float* q     = (const float*)d_in[2];
    const float* gamma = (const float*)d_in[3];
    const float* beta  = (const float*)d_in[4];
    float* out = (float*)d_out;

    // 4 images * 288 strips of 512 px = 1152 blocks; 4 phases of 128 px
    dnm_fused<<<dim3(1152), dim3(256), 0, stream>>>(x, Wg, q, gamma, beta, out);
}

// Round 12
// 77.944 us; speedup vs baseline: 1.0794x; 1.0243x over previous
//
#include <hip/hip_runtime.h>
#include <hip/hip_bf16.h>

typedef __attribute__((ext_vector_type(8))) short short8;
typedef __attribute__((ext_vector_type(4))) float f32x4;
typedef __attribute__((ext_vector_type(4))) unsigned int u32x4;

#define HWPIX 147456   // 384*384
#define NC 64
#define NO 64
#define NM 4
#define EPSV 1e-5f

// f32 pair -> packed bf16x2, round-to-nearest-even (hardware instruction).
static __device__ __forceinline__ unsigned int cvt_pk(float a, float b) {
    unsigned int r;
    asm("v_cvt_pk_bf16_f32 %0, %1, %2" : "=v"(r) : "v"(a), "v"(b));
    return r;
}
static __device__ __forceinline__ float asf(unsigned int u) {
    return __uint_as_float(u);
}

// raw barrier: LDS-visibility only, keeps global loads in flight (T4)
#define BAR() do { asm volatile("s_waitcnt lgkmcnt(0)" ::: "memory"); \
                   __builtin_amdgcn_s_barrier();                      \
                   asm volatile("" ::: "memory"); } while (0)

// R9-proven skeleton: LayerNorm -> stacked 1x1 conv -> sum_m relu(z-q).
// A = xn-hi (LDS dbuf, XOR-swizzled), B = gamma*W split hi/lo (regs),
// beta folded into acc init.  2-term split: xh*Wh + xh*Wl.
// Epilogue: sum_m max(z,q) - 4q.  1-deep prefetch after BAR.
// R12: grid = 1024 blocks (exactly 4 blocks/CU at VGPR<=128 tier) x 576 px
// (9 iters) -> zero dispatch tail.  256 blocks/image, no straddle.
__global__ __launch_bounds__(256) void dnm_fused(
    const float* __restrict__ x, const float* __restrict__ Wg,
    const float* __restrict__ qp, const float* __restrict__ gamma,
    const float* __restrict__ beta, float* __restrict__ out)
{
    // per buffer: xn-hi. Row = pixel (64 rows x 128B of bf16[64]),
    // 16B slots swizzled: byte = r*128 + ((slot ^ (r&7))<<4)
    __shared__ __align__(16) unsigned char lds[2][8192];

    const int tid = threadIdx.x;
    const int wv  = tid >> 6;        // wave 0..3 (owns o-slice wv*16..+16)
    const int ln  = tid & 63;
    const int p16 = ln & 15;
    const int g4  = ln >> 4;         // k-chunk group 0..3

    const int bid = blockIdx.x;      // 1024 blocks: 256 per image, 576 px each
    const int b       = bid >> 8;
    const int pixbase = (bid & 255) * 576;

    const float qv = qp[0];
    const float q4 = 4.0f * qv;

    // ---- B operand: W' = gamma .* W split hi/lo; bias[m] = sum_c beta_c*W[m][o][c]
    // lane holds row o = wv*16+p16, k = ch*32 + g4*8 + j
    f32x4 gA[2], gB[2], bA[2], bB[2];
#pragma unroll
    for (int ch = 0; ch < 2; ++ch) {
        gA[ch] = *(const f32x4*)(gamma + ch * 32 + g4 * 8);
        gB[ch] = *(const f32x4*)(gamma + ch * 32 + g4 * 8 + 4);
        bA[ch] = *(const f32x4*)(beta  + ch * 32 + g4 * 8);
        bB[ch] = *(const f32x4*)(beta  + ch * 32 + g4 * 8 + 4);
    }
    short8 wh[NM][2], wl[NM][2];
    float bias[NM];
#pragma unroll
    for (int m = 0; m < NM; ++m) {
        float bsum = 0.f;
#pragma unroll
        for (int ch = 0; ch < 2; ++ch) {
            const float* wp = Wg + ((m * NO + (wv * 16 + p16)) * NC + ch * 32 + g4 * 8);
            f32x4 a = *(const f32x4*)(wp);
            f32x4 c = *(const f32x4*)(wp + 4);
            float f[8]  = {a[0], a[1], a[2], a[3], c[0], c[1], c[2], c[3]};
            float gg[8] = {gA[ch][0], gA[ch][1], gA[ch][2], gA[ch][3],
                           gB[ch][0], gB[ch][1], gB[ch][2], gB[ch][3]};
            float bb[8] = {bA[ch][0], bA[ch][1], bA[ch][2], bA[ch][3],
                           bB[ch][0], bB[ch][1], bB[ch][2], bB[ch][3]};
            float wq[8];
#pragma unroll
            for (int j = 0; j < 8; ++j) {
                bsum += bb[j] * f[j];
                wq[j] = gg[j] * f[j];
            }
            u32x4 hu, lu;
#pragma unroll
            for (int p = 0; p < 4; ++p) {
                unsigned int h = cvt_pk(wq[2*p], wq[2*p+1]);
                float r0 = wq[2*p]   - asf(h << 16);          // bf2f(hi.lo) free
                float r1 = wq[2*p+1] - asf(h & 0xffff0000u);  // bf2f(hi.hi) free
                hu[p] = h;
                lu[p] = cvt_pk(r0, r1);
            }
            wh[m][ch] = __builtin_bit_cast(short8, hu);
            wl[m][ch] = __builtin_bit_cast(short8, lu);
        }
        bsum += __shfl_xor(bsum, 16);
        bsum += __shfl_xor(bsum, 32);   // full sum over c for this o
        bias[m] = bsum;
    }

    const float* xpl = x + (size_t)b * NC * HWPIX + pixbase + wv * 16 + p16
                         + (size_t)(g4 * 16) * HWPIX;
    float* const outw = out + (size_t)b * NO * HWPIX
                            + (size_t)(wv * 16 + p16) * HWPIX + pixbase;

    const int r  = wv * 16 + p16;    // LDS row this lane writes
    const int rk = r & 7;

    // prologue: loads for it=0
    float xv[16];
#pragma unroll
    for (int i = 0; i < 16; ++i) xv[i] = xpl[(size_t)i * HWPIX];

#pragma unroll 1
    for (int it = 0; it < 9; ++it) {
        unsigned char* buf = lds[it & 1];

        // ---- LN on prefetched xv (this wave's 16-px subtile, once per pixel)
        {
            float s1 = 0.f, s2 = 0.f;
#pragma unroll
            for (int i = 0; i < 16; ++i) { s1 += xv[i]; s2 += xv[i] * xv[i]; }
            s1 += __shfl_xor(s1, 16);  s2 += __shfl_xor(s2, 16);
            s1 += __shfl_xor(s1, 32);  s2 += __shfl_xor(s2, 32);
            const float mu  = s1 * (1.f / 64.f);
            const float var = s2 * (1.f / 64.f) - mu * mu;   // biased (torch)
            const float rs  = rsqrtf(var + EPSV);
            u32x4 h0, h1;
#pragma unroll
            for (int p = 0; p < 4; ++p) {
                h0[p] = cvt_pk((xv[2*p]     - mu) * rs, (xv[2*p+1] - mu) * rs);
                h1[p] = cvt_pk((xv[8+2*p]   - mu) * rs, (xv[9+2*p] - mu) * rs);
            }
            const int s0 = g4 * 2;
            *(u32x4*)(buf + r * 128 + (((s0    ) ^ rk) << 4)) = h0;
            *(u32x4*)(buf + r * 128 + (((s0 + 1) ^ rk) << 4)) = h1;
        }
        BAR();

        // ---- prefetch next tile's x (in flight across the MFMA phase)
        if (it < 8) {
            const float* xp = xpl + (it + 1) * 64;
#pragma unroll
            for (int i = 0; i < 16; ++i) xv[i] = xp[(size_t)i * HWPIX];
        }

        // ---- MFMA: wave covers its o-slice for all 4 pixel-subtiles
#pragma unroll 1
        for (int ps = 0; ps < 4; ++ps) {
            const int row = ps * 16 + p16;
            const int rwk = row & 7;
            short8 ah[2];
#pragma unroll
            for (int ch = 0; ch < 2; ++ch) {
                const int slot = ch * 4 + g4;
                ah[ch] = *(const short8*)(buf + row * 128 + ((slot ^ rwk) << 4));
            }
            f32x4 acc[NM];
#pragma unroll
            for (int m = 0; m < NM; ++m) {
                f32x4 a = {bias[m], bias[m], bias[m], bias[m]};
#pragma unroll
                for (int ch = 0; ch < 2; ++ch) {
                    // 2-term split: xh*Wh + xh*Wl (R5/R8/R9-proven numerics)
                    a = __builtin_amdgcn_mfma_f32_16x16x32_bf16(ah[ch], wh[m][ch], a, 0, 0, 0);
                    a = __builtin_amdgcn_mfma_f32_16x16x32_bf16(ah[ch], wl[m][ch], a, 0, 0, 0);
                }
                acc[m] = a;
            }
            // sum_m relu(z-q) = sum_m max(z,q) - 4q (R4-proven);
            // D: col(p16)=o-local, row(g4*4+rr)=pixel-local
            f32x4 v;
#pragma unroll
            for (int rr = 0; rr < 4; ++rr) {
                v[rr] = (fmaxf(acc[0][rr], qv) + fmaxf(acc[1][rr], qv))
                      + (fmaxf(acc[2][rr], qv) + fmaxf(acc[3][rr], qv)) - q4;
            }
            *(f32x4*)(outw + it * 64 + ps * 16 + g4 * 4) = v;   // 4 consecutive px
        }
        // single barrier per iter: buffer b reused at it+2 is ordered by
        // BAR(it+1), which every wave reaches only after its it-phase reads.
    }
}

extern "C" void kernel_launch(void* const* d_in, const int* in_sizes, int n_in,
                              void* d_out, int out_size, void* d_ws, size_t ws_size,
                              hipStream_t stream) {
    const float* x     = (const float*)d_in[0];
    const float* Wg    = (const float*)d_in[1];
    const float* q     = (const float*)d_in[2];
    const float* gamma = (const float*)d_in[3];
    const float* beta  = (const float*)d_in[4];
    float* out = (float*)d_out;

    // 1024 blocks = exactly 4/CU on 256 CUs; 576 px/block, zero dispatch tail
    dnm_fused<<<dim3(1024), dim3(256), 0, stream>>>(x, Wg, q, gamma, beta, out);
}

// Round 13
// 76.305 us; speedup vs baseline: 1.1026x; 1.0215x over previous
//
#include <hip/hip_runtime.h>
#include <hip/hip_bf16.h>

typedef __attribute__((ext_vector_type(8))) short short8;
typedef __attribute__((ext_vector_type(4))) float f32x4;
typedef __attribute__((ext_vector_type(4))) unsigned int u32x4;

#define HWPIX 147456   // 384*384
#define NC 64
#define NO 64
#define NM 4
#define EPSV 1e-5f

// f32 pair -> packed bf16x2, round-to-nearest-even (hardware instruction).
static __device__ __forceinline__ unsigned int cvt_pk(float a, float b) {
    unsigned int r;
    asm("v_cvt_pk_bf16_f32 %0, %1, %2" : "=v"(r) : "v"(a), "v"(b));
    return r;
}
static __device__ __forceinline__ float asf(unsigned int u) {
    return __uint_as_float(u);
}

// raw barrier: LDS-visibility only, keeps global loads in flight (T4)
#define BAR() do { asm volatile("s_waitcnt lgkmcnt(0)" ::: "memory"); \
                   __builtin_amdgcn_s_barrier();                      \
                   asm volatile("" ::: "memory"); } while (0)

// R9-proven skeleton: LayerNorm -> stacked 1x1 conv -> sum_m relu(z-q).
// A = xn-hi (LDS dbuf, XOR-swizzled), B = gamma*W split hi/lo (regs),
// beta folded into acc init.  2-term split: xh*Wh + xh*Wl.
// Epilogue: sum_m max(z,q) - 4q.  1-deep prefetch after BAR.
// R13: ps-loop fully unrolled (only change vs R9) -> all 8 ds_read_b128
// issue early, 4 subtiles' MFMA chains interleave (intra-phase ILP).
__global__ __launch_bounds__(256) void dnm_fused(
    const float* __restrict__ x, const float* __restrict__ Wg,
    const float* __restrict__ qp, const float* __restrict__ gamma,
    const float* __restrict__ beta, float* __restrict__ out)
{
    // per buffer: xn-hi. Row = pixel (64 rows x 128B of bf16[64]),
    // 16B slots swizzled: byte = r*128 + ((slot ^ (r&7))<<4)
    __shared__ __align__(16) unsigned char lds[2][8192];

    const int tid = threadIdx.x;
    const int wv  = tid >> 6;        // wave 0..3 (owns o-slice wv*16..+16)
    const int ln  = tid & 63;
    const int p16 = ln & 15;
    const int g4  = ln >> 4;         // k-chunk group 0..3

    const int bid = blockIdx.x;      // 1152 blocks: 288 strips of 512 px per image
    const int b       = bid / 288;
    const int pixbase = (bid % 288) * 512;

    const float qv = qp[0];
    const float q4 = 4.0f * qv;

    // ---- B operand: W' = gamma .* W split hi/lo; bias[m] = sum_c beta_c*W[m][o][c]
    // lane holds row o = wv*16+p16, k = ch*32 + g4*8 + j
    f32x4 gA[2], gB[2], bA[2], bB[2];
#pragma unroll
    for (int ch = 0; ch < 2; ++ch) {
        gA[ch] = *(const f32x4*)(gamma + ch * 32 + g4 * 8);
        gB[ch] = *(const f32x4*)(gamma + ch * 32 + g4 * 8 + 4);
        bA[ch] = *(const f32x4*)(beta  + ch * 32 + g4 * 8);
        bB[ch] = *(const f32x4*)(beta  + ch * 32 + g4 * 8 + 4);
    }
    short8 wh[NM][2], wl[NM][2];
    float bias[NM];
#pragma unroll
    for (int m = 0; m < NM; ++m) {
        float bsum = 0.f;
#pragma unroll
        for (int ch = 0; ch < 2; ++ch) {
            const float* wp = Wg + ((m * NO + (wv * 16 + p16)) * NC + ch * 32 + g4 * 8);
            f32x4 a = *(const f32x4*)(wp);
            f32x4 c = *(const f32x4*)(wp + 4);
            float f[8]  = {a[0], a[1], a[2], a[3], c[0], c[1], c[2], c[3]};
            float gg[8] = {gA[ch][0], gA[ch][1], gA[ch][2], gA[ch][3],
                           gB[ch][0], gB[ch][1], gB[ch][2], gB[ch][3]};
            float bb[8] = {bA[ch][0], bA[ch][1], bA[ch][2], bA[ch][3],
                           bB[ch][0], bB[ch][1], bB[ch][2], bB[ch][3]};
            float wq[8];
#pragma unroll
            for (int j = 0; j < 8; ++j) {
                bsum += bb[j] * f[j];
                wq[j] = gg[j] * f[j];
            }
            u32x4 hu, lu;
#pragma unroll
            for (int p = 0; p < 4; ++p) {
                unsigned int h = cvt_pk(wq[2*p], wq[2*p+1]);
                float r0 = wq[2*p]   - asf(h << 16);          // bf2f(hi.lo) free
                float r1 = wq[2*p+1] - asf(h & 0xffff0000u);  // bf2f(hi.hi) free
                hu[p] = h;
                lu[p] = cvt_pk(r0, r1);
            }
            wh[m][ch] = __builtin_bit_cast(short8, hu);
            wl[m][ch] = __builtin_bit_cast(short8, lu);
        }
        bsum += __shfl_xor(bsum, 16);
        bsum += __shfl_xor(bsum, 32);   // full sum over c for this o
        bias[m] = bsum;
    }

    const float* xpl = x + (size_t)b * NC * HWPIX + pixbase + wv * 16 + p16
                         + (size_t)(g4 * 16) * HWPIX;
    float* const outw = out + (size_t)b * NO * HWPIX
                            + (size_t)(wv * 16 + p16) * HWPIX + pixbase;

    const int r  = wv * 16 + p16;    // LDS row this lane writes
    const int rk = r & 7;

    // prologue: loads for it=0
    float xv[16];
#pragma unroll
    for (int i = 0; i < 16; ++i) xv[i] = xpl[(size_t)i * HWPIX];

#pragma unroll 1
    for (int it = 0; it < 8; ++it) {
        unsigned char* buf = lds[it & 1];

        // ---- LN on prefetched xv (this wave's 16-px subtile, once per pixel)
        {
            float s1 = 0.f, s2 = 0.f;
#pragma unroll
            for (int i = 0; i < 16; ++i) { s1 += xv[i]; s2 += xv[i] * xv[i]; }
            s1 += __shfl_xor(s1, 16);  s2 += __shfl_xor(s2, 16);
            s1 += __shfl_xor(s1, 32);  s2 += __shfl_xor(s2, 32);
            const float mu  = s1 * (1.f / 64.f);
            const float var = s2 * (1.f / 64.f) - mu * mu;   // biased (torch)
            const float rs  = rsqrtf(var + EPSV);
            u32x4 h0, h1;
#pragma unroll
            for (int p = 0; p < 4; ++p) {
                h0[p] = cvt_pk((xv[2*p]     - mu) * rs, (xv[2*p+1] - mu) * rs);
                h1[p] = cvt_pk((xv[8+2*p]   - mu) * rs, (xv[9+2*p] - mu) * rs);
            }
            const int s0 = g4 * 2;
            *(u32x4*)(buf + r * 128 + (((s0    ) ^ rk) << 4)) = h0;
            *(u32x4*)(buf + r * 128 + (((s0 + 1) ^ rk) << 4)) = h1;
        }
        BAR();

        // ---- prefetch next tile's x (in flight across the MFMA phase)
        if (it < 7) {
            const float* xp = xpl + (it + 1) * 64;
#pragma unroll
            for (int i = 0; i < 16; ++i) xv[i] = xp[(size_t)i * HWPIX];
        }

        // ---- MFMA: wave covers its o-slice for all 4 pixel-subtiles.
        // R13: fully unrolled -> ds_reads hoist, MFMA chains interleave.
#pragma unroll
        for (int ps = 0; ps < 4; ++ps) {
            const int row = ps * 16 + p16;
            const int rwk = row & 7;
            short8 ah[2];
#pragma unroll
            for (int ch = 0; ch < 2; ++ch) {
                const int slot = ch * 4 + g4;
                ah[ch] = *(const short8*)(buf + row * 128 + ((slot ^ rwk) << 4));
            }
            f32x4 acc[NM];
#pragma unroll
            for (int m = 0; m < NM; ++m) {
                f32x4 a = {bias[m], bias[m], bias[m], bias[m]};
#pragma unroll
                for (int ch = 0; ch < 2; ++ch) {
                    // 2-term split: xh*Wh + xh*Wl (R5/R8/R9-proven numerics)
                    a = __builtin_amdgcn_mfma_f32_16x16x32_bf16(ah[ch], wh[m][ch], a, 0, 0, 0);
                    a = __builtin_amdgcn_mfma_f32_16x16x32_bf16(ah[ch], wl[m][ch], a, 0, 0, 0);
                }
                acc[m] = a;
            }
            // sum_m relu(z-q) = sum_m max(z,q) - 4q (R4-proven);
            // D: col(p16)=o-local, row(g4*4+rr)=pixel-local
            f32x4 v;
#pragma unroll
            for (int rr = 0; rr < 4; ++rr) {
                v[rr] = (fmaxf(acc[0][rr], qv) + fmaxf(acc[1][rr], qv))
                      + (fmaxf(acc[2][rr], qv) + fmaxf(acc[3][rr], qv)) - q4;
            }
            *(f32x4*)(outw + it * 64 + ps * 16 + g4 * 4) = v;   // 4 consecutive px
        }
        // single barrier per iter: buffer b reused at it+2 is ordered by
        // BAR(it+1), which every wave reaches only after its it-phase reads.
    }
}

extern "C" void kernel_launch(void* const* d_in, const int* in_sizes, int n_in,
                              void* d_out, int out_size, void* d_ws, size_t ws_size,
                              hipStream_t stream) {
    const float* x     = (const float*)d_in[0];
    const float* Wg    = (const float*)d_in[1];
    const float* q     = (const float*)d_in[2];
    const float* gamma = (const float*)d_in[3];
    const float* beta  = (const float*)d_in[4];
    float* out = (float*)d_out;

    // 4 images * 288 strips of 512 px = 1152 blocks (R9 grid)
    dnm_fused<<<dim3(1152), dim3(256), 0, stream>>>(x, Wg, q, gamma, beta, out);
}

// Round 14
// 69.788 us; speedup vs baseline: 1.2055x; 1.0934x over previous
//
#include <hip/hip_runtime.h>
#include <hip/hip_bf16.h>

typedef __attribute__((ext_vector_type(8))) short short8;
typedef __attribute__((ext_vector_type(4))) float f32x4;
typedef __attribute__((ext_vector_type(4))) unsigned int u32x4;

#define HWPIX 147456   // 384*384
#define NC 64
#define NO 64
#define NM 4
#define EPSV 1e-5f

// f32 pair -> packed bf16x2, round-to-nearest-even (hardware instruction).
static __device__ __forceinline__ unsigned int cvt_pk(float a, float b) {
    unsigned int r;
    asm("v_cvt_pk_bf16_f32 %0, %1, %2" : "=v"(r) : "v"(a), "v"(b));
    return r;
}
static __device__ __forceinline__ float asf(unsigned int u) {
    return __uint_as_float(u);
}

// raw barrier: LDS-visibility only, keeps global loads in flight (T4)
#define BAR() do { asm volatile("s_waitcnt lgkmcnt(0)" ::: "memory"); \
                   __builtin_amdgcn_s_barrier();                      \
                   asm volatile("" ::: "memory"); } while (0)

// R9-proven skeleton: LayerNorm -> stacked 1x1 conv -> sum_m relu(z-q).
// A = xn-hi (LDS dbuf, XOR-swizzled), B = gamma*W split hi/lo (regs),
// beta folded into acc init.  2-term split: xh*Wh + xh*Wl.
// Epilogue: sum_m max(z,q) - 4q.  1-deep prefetch after BAR.
// R14: output stores are NON-TEMPORAL (bypass L2/L3) so the write-once out
// stream stops evicting x from Infinity Cache -> lower HBM FETCH.
__global__ __launch_bounds__(256) void dnm_fused(
    const float* __restrict__ x, const float* __restrict__ Wg,
    const float* __restrict__ qp, const float* __restrict__ gamma,
    const float* __restrict__ beta, float* __restrict__ out)
{
    // per buffer: xn-hi. Row = pixel (64 rows x 128B of bf16[64]),
    // 16B slots swizzled: byte = r*128 + ((slot ^ (r&7))<<4)
    __shared__ __align__(16) unsigned char lds[2][8192];

    const int tid = threadIdx.x;
    const int wv  = tid >> 6;        // wave 0..3 (owns o-slice wv*16..+16)
    const int ln  = tid & 63;
    const int p16 = ln & 15;
    const int g4  = ln >> 4;         // k-chunk group 0..3

    const int bid = blockIdx.x;      // 1152 blocks: 288 strips of 512 px per image
    const int b       = bid / 288;
    const int pixbase = (bid % 288) * 512;

    const float qv = qp[0];
    const float q4 = 4.0f * qv;

    // ---- B operand: W' = gamma .* W split hi/lo; bias[m] = sum_c beta_c*W[m][o][c]
    // lane holds row o = wv*16+p16, k = ch*32 + g4*8 + j
    f32x4 gA[2], gB[2], bA[2], bB[2];
#pragma unroll
    for (int ch = 0; ch < 2; ++ch) {
        gA[ch] = *(const f32x4*)(gamma + ch * 32 + g4 * 8);
        gB[ch] = *(const f32x4*)(gamma + ch * 32 + g4 * 8 + 4);
        bA[ch] = *(const f32x4*)(beta  + ch * 32 + g4 * 8);
        bB[ch] = *(const f32x4*)(beta  + ch * 32 + g4 * 8 + 4);
    }
    short8 wh[NM][2], wl[NM][2];
    float bias[NM];
#pragma unroll
    for (int m = 0; m < NM; ++m) {
        float bsum = 0.f;
#pragma unroll
        for (int ch = 0; ch < 2; ++ch) {
            const float* wp = Wg + ((m * NO + (wv * 16 + p16)) * NC + ch * 32 + g4 * 8);
            f32x4 a = *(const f32x4*)(wp);
            f32x4 c = *(const f32x4*)(wp + 4);
            float f[8]  = {a[0], a[1], a[2], a[3], c[0], c[1], c[2], c[3]};
            float gg[8] = {gA[ch][0], gA[ch][1], gA[ch][2], gA[ch][3],
                           gB[ch][0], gB[ch][1], gB[ch][2], gB[ch][3]};
            float bb[8] = {bA[ch][0], bA[ch][1], bA[ch][2], bA[ch][3],
                           bB[ch][0], bB[ch][1], bB[ch][2], bB[ch][3]};
            float wq[8];
#pragma unroll
            for (int j = 0; j < 8; ++j) {
                bsum += bb[j] * f[j];
                wq[j] = gg[j] * f[j];
            }
            u32x4 hu, lu;
#pragma unroll
            for (int p = 0; p < 4; ++p) {
                unsigned int h = cvt_pk(wq[2*p], wq[2*p+1]);
                float r0 = wq[2*p]   - asf(h << 16);          // bf2f(hi.lo) free
                float r1 = wq[2*p+1] - asf(h & 0xffff0000u);  // bf2f(hi.hi) free
                hu[p] = h;
                lu[p] = cvt_pk(r0, r1);
            }
            wh[m][ch] = __builtin_bit_cast(short8, hu);
            wl[m][ch] = __builtin_bit_cast(short8, lu);
        }
        bsum += __shfl_xor(bsum, 16);
        bsum += __shfl_xor(bsum, 32);   // full sum over c for this o
        bias[m] = bsum;
    }

    const float* xpl = x + (size_t)b * NC * HWPIX + pixbase + wv * 16 + p16
                         + (size_t)(g4 * 16) * HWPIX;
    float* const outw = out + (size_t)b * NO * HWPIX
                            + (size_t)(wv * 16 + p16) * HWPIX + pixbase;

    const int r  = wv * 16 + p16;    // LDS row this lane writes
    const int rk = r & 7;

    // prologue: loads for it=0
    float xv[16];
#pragma unroll
    for (int i = 0; i < 16; ++i) xv[i] = xpl[(size_t)i * HWPIX];

#pragma unroll 1
    for (int it = 0; it < 8; ++it) {
        unsigned char* buf = lds[it & 1];

        // ---- LN on prefetched xv (this wave's 16-px subtile, once per pixel)
        {
            float s1 = 0.f, s2 = 0.f;
#pragma unroll
            for (int i = 0; i < 16; ++i) { s1 += xv[i]; s2 += xv[i] * xv[i]; }
            s1 += __shfl_xor(s1, 16);  s2 += __shfl_xor(s2, 16);
            s1 += __shfl_xor(s1, 32);  s2 += __shfl_xor(s2, 32);
            const float mu  = s1 * (1.f / 64.f);
            const float var = s2 * (1.f / 64.f) - mu * mu;   // biased (torch)
            const float rs  = rsqrtf(var + EPSV);
            u32x4 h0, h1;
#pragma unroll
            for (int p = 0; p < 4; ++p) {
                h0[p] = cvt_pk((xv[2*p]     - mu) * rs, (xv[2*p+1] - mu) * rs);
                h1[p] = cvt_pk((xv[8+2*p]   - mu) * rs, (xv[9+2*p] - mu) * rs);
            }
            const int s0 = g4 * 2;
            *(u32x4*)(buf + r * 128 + (((s0    ) ^ rk) << 4)) = h0;
            *(u32x4*)(buf + r * 128 + (((s0 + 1) ^ rk) << 4)) = h1;
        }
        BAR();

        // ---- prefetch next tile's x (in flight across the MFMA phase)
        if (it < 7) {
            const float* xp = xpl + (it + 1) * 64;
#pragma unroll
            for (int i = 0; i < 16; ++i) xv[i] = xp[(size_t)i * HWPIX];
        }

        // ---- MFMA: wave covers its o-slice for all 4 pixel-subtiles
#pragma unroll 1
        for (int ps = 0; ps < 4; ++ps) {
            const int row = ps * 16 + p16;
            const int rwk = row & 7;
            short8 ah[2];
#pragma unroll
            for (int ch = 0; ch < 2; ++ch) {
                const int slot = ch * 4 + g4;
                ah[ch] = *(const short8*)(buf + row * 128 + ((slot ^ rwk) << 4));
            }
            f32x4 acc[NM];
#pragma unroll
            for (int m = 0; m < NM; ++m) {
                f32x4 a = {bias[m], bias[m], bias[m], bias[m]};
#pragma unroll
                for (int ch = 0; ch < 2; ++ch) {
                    // 2-term split: xh*Wh + xh*Wl (R5/R8/R9-proven numerics)
                    a = __builtin_amdgcn_mfma_f32_16x16x32_bf16(ah[ch], wh[m][ch], a, 0, 0, 0);
                    a = __builtin_amdgcn_mfma_f32_16x16x32_bf16(ah[ch], wl[m][ch], a, 0, 0, 0);
                }
                acc[m] = a;
            }
            // sum_m relu(z-q) = sum_m max(z,q) - 4q (R4-proven);
            // D: col(p16)=o-local, row(g4*4+rr)=pixel-local
            f32x4 v;
#pragma unroll
            for (int rr = 0; rr < 4; ++rr) {
                v[rr] = (fmaxf(acc[0][rr], qv) + fmaxf(acc[1][rr], qv))
                      + (fmaxf(acc[2][rr], qv) + fmaxf(acc[3][rr], qv)) - q4;
            }
            // non-temporal: write-once stream, keep it out of L2/L3
            __builtin_nontemporal_store(
                v, (f32x4*)(outw + it * 64 + ps * 16 + g4 * 4));
        }
        // single barrier per iter: buffer b reused at it+2 is ordered by
        // BAR(it+1), which every wave reaches only after its it-phase reads.
    }
}

extern "C" void kernel_launch(void* const* d_in, const int* in_sizes, int n_in,
                              void* d_out, int out_size, void* d_ws, size_t ws_size,
                              hipStream_t stream) {
    const float* x     = (const float*)d_in[0];
    const float* Wg    = (const float*)d_in[1];
    const float* q     = (const float*)d_in[2];
    const float* gamma = (const float*)d_in[3];
    const float* beta  = (const float*)d_in[4];
    float* out = (float*)d_out;

    // 4 images * 288 strips of 512 px = 1152 blocks (R9 grid)
    dnm_fused<<<dim3(1152), dim3(256), 0, stream>>>(x, Wg, q, gamma, beta, out);
}